// Round 5
// baseline (182.444 us; speedup 1.0000x reference)
//
#include <hip/hip_runtime.h>

// B=2, T=2048, C=1024, H=16, hd=64, LOCAL_WINDOW=512, MAX_REL_DIST=128
#define T_SEQ 2048
#define HD 64

typedef float f32x4 __attribute__((ext_vector_type(4)));
typedef __bf16 bf16x8 __attribute__((ext_vector_type(8)));
typedef unsigned short ushort4v __attribute__((ext_vector_type(4)));
typedef unsigned short ushort8v __attribute__((ext_vector_type(8)));

__device__ __forceinline__ unsigned short f2bf(float f) {
    unsigned u = __builtin_bit_cast(unsigned, f);
    u += 0x7fffu + ((u >> 16) & 1u);
    return (unsigned short)(u >> 16);
}

__device__ __forceinline__ void gll16(const void* g, void* lds) {
    __builtin_amdgcn_global_load_lds(
        (const __attribute__((address_space(1))) unsigned int*)g,
        (__attribute__((address_space(3))) unsigned int*)lds, 16, 0, 0);
}

__device__ __forceinline__ bf16x8 ldfrag(const unsigned short* p) {
    return __builtin_bit_cast(bf16x8, *reinterpret_cast<const ushort8v*>(p));
}

// fused fp32->bf16 convert for x / w_qkv / w_proj (one launch)
__global__ __launch_bounds__(256)
void cvt_all_kernel(const float* __restrict__ x, const float* __restrict__ wq,
                    const float* __restrict__ wp, unsigned short* __restrict__ xb,
                    unsigned short* __restrict__ wqb, unsigned short* __restrict__ wpb)
{
    int bid = blockIdx.x;
    const float* s; unsigned short* d; int off;
    if (bid < 2048)      { s = x;  d = xb;  off = bid; }
    else if (bid < 3584) { s = wq; d = wqb; off = bid - 2048; }
    else                 { s = wp; d = wpb; off = bid - 3584; }
    int i = (off * 256 + threadIdx.x) * 8;
    f32x4 a = *reinterpret_cast<const f32x4*>(s + i);
    f32x4 b = *reinterpret_cast<const f32x4*>(s + i + 4);
    ushort8v o;
#pragma unroll
    for (int j = 0; j < 4; ++j) { o[j] = f2bf(a[j]); o[4 + j] = f2bf(b[j]); }
    *reinterpret_cast<ushort8v*>(d + i) = o;
}

// QKV GEMM: out[n][m] = sum_k A[n][k]*W[m][k], K=1024, 128x128 tile, 256 thr.
// q stored TRANSPOSED (B,H,hd,T) pre-scaled by 0.125 (b64 stores);
// k stored (B,H,T,hd) (scalar stores, needed as MFMA A-operand);
// v stored TRANSPOSED (B,H,hd,T) (b64 stores).
__global__ __launch_bounds__(256)
void gemm_qkv_kernel(const unsigned short* __restrict__ A, const unsigned short* __restrict__ W,
                     unsigned short* __restrict__ qo, unsigned short* __restrict__ ko,
                     unsigned short* __restrict__ vo)
{
    constexpr int K = 1024;
    __shared__ unsigned short As[128 * 32];
    __shared__ unsigned short Bs[128 * 32];
    const int t = threadIdx.x;
    const int m0 = blockIdx.x * 128, n0 = blockIdx.y * 128;
    const int lane = t & 63, w = t >> 6;
    const int wy = w >> 1, wx = w & 1;
    const int l15 = lane & 15, quad = lane >> 4;

    f32x4 acc[4][4] = {};
    const char* Ab = (const char*)A;
    const char* Wb = (const char*)W;

    for (int kcl = 0; kcl < K; kcl += 32) {
#pragma unroll
        for (int i = 0; i < 2; ++i) {
            int c = w * 2 + i;                  // 1KB chunk 0..7
            int lin = c * 1024 + lane * 16;
            int row = lin >> 6;
            int kc = ((lin & 63) >> 4) ^ (row & 3);   // xor-swizzled 16B chunk
            gll16(Ab + ((size_t)(n0 + row) * K + kcl + kc * 8) * 2, (char*)As + c * 1024);
            gll16(Wb + ((size_t)(m0 + row) * K + kcl + kc * 8) * 2, (char*)Bs + c * 1024);
        }
        __syncthreads();
        bf16x8 af[4], bfr[4];
#pragma unroll
        for (int nt = 0; nt < 4; ++nt)
            af[nt] = ldfrag(As + (wy * 64 + nt * 16 + l15) * 32 + ((quad ^ (l15 & 3)) * 8));
#pragma unroll
        for (int mt = 0; mt < 4; ++mt)
            bfr[mt] = ldfrag(Bs + (wx * 64 + mt * 16 + l15) * 32 + ((quad ^ (l15 & 3)) * 8));
#pragma unroll
        for (int nt = 0; nt < 4; ++nt)
#pragma unroll
            for (int mt = 0; mt < 4; ++mt)
                acc[nt][mt] = __builtin_amdgcn_mfma_f32_16x16x32_bf16(af[nt], bfr[mt], acc[nt][mt], 0, 0, 0);
        __syncthreads();
    }

    const int s = m0 >> 10;   // block-uniform: which of q/k/v this block writes
#pragma unroll
    for (int nt = 0; nt < 4; ++nt) {
#pragma unroll
        for (int mt = 0; mt < 4; ++mt) {
            const int m = m0 + wx * 64 + mt * 16 + l15;
            const int h = (m >> 6) & 15, d = m & 63;
            const int n = n0 + wy * 64 + nt * 16 + quad * 4;   // +r, r=0..3 contiguous
            const int bb = n >> 11, tt = n & 2047;
            if (s == 1) {
#pragma unroll
                for (int r = 0; r < 4; ++r)
                    ko[((size_t)((bb << 4) + h) * T_SEQ + tt + r) * HD + d] = f2bf(acc[nt][mt][r]);
            } else {
                ushort4v o;
                if (s == 0) {
#pragma unroll
                    for (int r = 0; r < 4; ++r) o[r] = f2bf(acc[nt][mt][r] * 0.125f);
                    *reinterpret_cast<ushort4v*>(qo + ((size_t)((bb << 4) + h) * HD + d) * T_SEQ + tt) = o;
                } else {
#pragma unroll
                    for (int r = 0; r < 4; ++r) o[r] = f2bf(acc[nt][mt][r]);
                    *reinterpret_cast<ushort4v*>(vo + ((size_t)((bb << 4) + h) * HD + d) * T_SEQ + tt) = o;
                }
            }
        }
    }
}

// Proj GEMM: 512 threads (8 waves 4x2), 128x128 tile, out fp32 + bias.
__global__ __launch_bounds__(512, 4)
void gemm_proj_kernel(const unsigned short* __restrict__ A, const unsigned short* __restrict__ W,
                      float* __restrict__ o0, const float* __restrict__ bias)
{
    constexpr int K = 1024;
    __shared__ unsigned short As[128 * 32];
    __shared__ unsigned short Bs[128 * 32];
    const int t = threadIdx.x;
    const int m0 = blockIdx.x * 128, n0 = blockIdx.y * 128;
    const int lane = t & 63, w = t >> 6;
    const int wy = w >> 1, wx = w & 1;     // 4 (n) x 2 (m) waves; wave = 32n x 64m
    const int l15 = lane & 15, quad = lane >> 4;

    f32x4 acc[2][4] = {};
    const char* Ab = (const char*)A;
    const char* Wb = (const char*)W;
    const int srow = t >> 2;
    const int skc = (t & 3) ^ (srow & 3);

    for (int kcl = 0; kcl < K; kcl += 32) {
        gll16(Ab + ((size_t)(n0 + srow) * K + kcl + skc * 8) * 2, (char*)As + w * 1024);
        gll16(Wb + ((size_t)(m0 + srow) * K + kcl + skc * 8) * 2, (char*)Bs + w * 1024);
        __syncthreads();
        bf16x8 af[2], bfr[4];
#pragma unroll
        for (int nt = 0; nt < 2; ++nt)
            af[nt] = ldfrag(As + (wy * 32 + nt * 16 + l15) * 32 + ((quad ^ (l15 & 3)) * 8));
#pragma unroll
        for (int mt = 0; mt < 4; ++mt)
            bfr[mt] = ldfrag(Bs + (wx * 64 + mt * 16 + l15) * 32 + ((quad ^ (l15 & 3)) * 8));
#pragma unroll
        for (int nt = 0; nt < 2; ++nt)
#pragma unroll
            for (int mt = 0; mt < 4; ++mt)
                acc[nt][mt] = __builtin_amdgcn_mfma_f32_16x16x32_bf16(af[nt], bfr[mt], acc[nt][mt], 0, 0, 0);
        __syncthreads();
    }

#pragma unroll
    for (int nt = 0; nt < 2; ++nt)
#pragma unroll
        for (int mt = 0; mt < 4; ++mt) {
            const int m = m0 + wx * 64 + mt * 16 + l15;
            const float bm = bias[m];
#pragma unroll
            for (int r = 0; r < 4; ++r) {
                const int n = n0 + wy * 32 + nt * 16 + quad * 4 + r;
                o0[(size_t)n * 1024 + m] = acc[nt][mt][r] + bm;
            }
        }
}

// S^T-formulation MFMA flash attention.
// grid (T/128, B*H), 512 threads = 8 waves; wave owns 16 q rows (q = q0+w*16+l15 per lane).
// S^T = K Q^T (A=K, B=Q from Q^T global): lane holds 1 q-col, keys quad*4+r per 16-tile.
// O^T = V^T P (A=V^T from pre-transposed V, B=P via vectorized LDS round trip).
__global__ __launch_bounds__(512, 4)
void attn_kernel(const unsigned short* __restrict__ qt_g, const unsigned short* __restrict__ kg,
                 const unsigned short* __restrict__ vt, const float* __restrict__ rel_bias,
                 unsigned short* __restrict__ y)
{
    __shared__ unsigned short Ks[64 * 64];      // K tile [key][hd], 16B chunks xor-swizzled
    __shared__ unsigned short Vt[64 * 64];      // V^T tile [hd][key], same swizzle
    __shared__ unsigned short Pl[8 * 16 * 72];  // per-wave P [q(16)][key(64)+pad]
    __shared__ float bias_s[260];

    const int t = threadIdx.x;
    const int lane = t & 63, w = t >> 6;
    const int l15 = lane & 15, quad = lane >> 4;
    const int qt = blockIdx.x, bh = blockIdx.y;
    const int b = bh >> 4, h = bh & 15;
    const int q0 = qt << 7;
    const int qw0 = q0 + w * 16;
    const int q_row = qw0 + l15;
    const size_t base = (size_t)bh * T_SEQ * HD;   // same stride for k, q^t, v^t

    for (int i = t; i < 257; i += 512) bias_s[i] = rel_bias[i * 16 + h];

    // Q fragments (B operand: lane l15 = q col, k = quad*8+j) gathered from Q^T (B,H,hd,T).
    // 16 scalar loads, once per block. Scale pre-applied by producer.
    bf16x8 qf[2];
    {
        const unsigned short* qp = qt_g + base + q_row;
#pragma unroll
        for (int ks = 0; ks < 2; ++ks) {
            ushort8v tmp;
#pragma unroll
            for (int j = 0; j < 8; ++j)
                tmp[j] = qp[(size_t)(ks * 32 + quad * 8 + j) * T_SEQ];
            qf[ks] = __builtin_bit_cast(bf16x8, tmp);
        }
    }

    float m_r = -1e30f, l_r = 0.f;
    f32x4 Oacc[4] = {};                          // [mt over hd], col = q

    unsigned short* Pme = Pl + w * (16 * 72);
    // staging map: thread stages one 16B chunk of K and of V^T
    const int srow = t >> 3;                     // 0..63
    const int skc = (t & 7) ^ (srow & 7);        // global 16B chunk (xor-swizzled slot)

    const int kt0 = (qt * 2 > 8) ? (qt * 2 - 8) : 0;
    const int kt1 = qt * 2 + 1;

    for (int kt = kt0; kt <= kt1; ++kt) {
        gll16((const char*)(kg + base + (size_t)(kt * 64 + srow) * HD + skc * 8), (char*)Ks + w * 1024);
        gll16((const char*)(vt + base + (size_t)srow * T_SEQ + kt * 64 + skc * 8), (char*)Vt + w * 1024);
        __syncthreads();

        const int delta = qw0 - kt * 64;         // wave-uniform
        if (delta >= 0 && delta <= 560) {        // wave has work this tile
            // S^T = K Q^T
            f32x4 Sacc[4] = {};
#pragma unroll
            for (int ks = 0; ks < 2; ++ks)
#pragma unroll
                for (int ct = 0; ct < 4; ++ct) {
                    bf16x8 kf = ldfrag(Ks + (ct * 16 + l15) * 64 + (((ks * 4 + quad) ^ (l15 & 7)) * 8));
                    Sacc[ct] = __builtin_amdgcn_mfma_f32_16x16x32_bf16(kf, qf[ks], Sacc[ct], 0, 0, 0);
                }

            float sv[4][4];
            if (delta >= 192 && delta <= 496) {
                // fast path: no mask possible, bias == bias[256] for all pairs
                const float bC = bias_s[256];
#pragma unroll
                for (int ct = 0; ct < 4; ++ct)
#pragma unroll
                    for (int r = 0; r < 4; ++r) sv[ct][r] = Sacc[ct][r] + bC;
            } else {
#pragma unroll
                for (int ct = 0; ct < 4; ++ct)
#pragma unroll
                    for (int r = 0; r < 4; ++r) {
                        int diff = q_row - (kt * 64 + ct * 16 + quad * 4 + r);
                        float bb = bias_s[(diff < 128 ? diff : 128) + 128];
                        float s = Sacc[ct][r] + bb;
                        sv[ct][r] = (diff < 0 || diff > 512) ? -1e30f : s;
                    }
            }

            // online softmax (per-lane scalar state; reduce across quad groups)
            float mx = -1e30f;
#pragma unroll
            for (int ct = 0; ct < 4; ++ct)
#pragma unroll
                for (int r = 0; r < 4; ++r) mx = fmaxf(mx, sv[ct][r]);
            mx = fmaxf(mx, __shfl_xor(mx, 16, 64));
            mx = fmaxf(mx, __shfl_xor(mx, 32, 64));
            float mn = fmaxf(m_r, mx);
            float alpha = __expf(m_r - mn);
            m_r = mn;
            float ps = 0.f;
            float p[4][4];
#pragma unroll
            for (int ct = 0; ct < 4; ++ct)
#pragma unroll
                for (int r = 0; r < 4; ++r) { p[ct][r] = __expf(sv[ct][r] - mn); ps += p[ct][r]; }
            ps += __shfl_xor(ps, 16, 64);
            ps += __shfl_xor(ps, 32, 64);
            l_r = l_r * alpha + ps;

            // P -> wave-private LDS (vectorized b64: lane's 4 keys are contiguous)
#pragma unroll
            for (int ct = 0; ct < 4; ++ct) {
                ushort4v pw;
#pragma unroll
                for (int j = 0; j < 4; ++j) pw[j] = f2bf(p[ct][j]);
                *reinterpret_cast<ushort4v*>(Pme + l15 * 72 + ct * 16 + quad * 4) = pw;
            }
#pragma unroll
            for (int mt = 0; mt < 4; ++mt) Oacc[mt] *= alpha;
#pragma unroll
            for (int ks = 0; ks < 2; ++ks) {
                bf16x8 pf = ldfrag(Pme + l15 * 72 + ks * 32 + quad * 8);
#pragma unroll
                for (int mt = 0; mt < 4; ++mt) {
                    bf16x8 vf = ldfrag(Vt + (mt * 16 + l15) * 64 + (((ks * 4 + quad) ^ (l15 & 7)) * 8));
                    Oacc[mt] = __builtin_amdgcn_mfma_f32_16x16x32_bf16(vf, pf, Oacc[mt], 0, 0, 0);
                }
            }
        }
        __syncthreads();
    }

    // normalize + write: lane's 16 outputs are one q row, contiguous per mt (b64 stores)
    const float inv = 1.0f / l_r;
    unsigned short* yp = y + ((size_t)b * T_SEQ + q_row) * 1024 + h * 64;
#pragma unroll
    for (int mt = 0; mt < 4; ++mt) {
        ushort4v o;
#pragma unroll
        for (int j = 0; j < 4; ++j) o[j] = f2bf(Oacc[mt][j] * inv);
        *reinterpret_cast<ushort4v*>(yp + mt * 16 + quad * 4) = o;
    }
}

extern "C" void kernel_launch(void* const* d_in, const int* in_sizes, int n_in,
                              void* d_out, int out_size, void* d_ws, size_t ws_size,
                              hipStream_t stream)
{
    (void)in_sizes; (void)n_in; (void)out_size; (void)ws_size;
    const float* x        = (const float*)d_in[0];
    const float* w_qkv    = (const float*)d_in[1];
    const float* w_proj   = (const float*)d_in[2];
    const float* b_proj   = (const float*)d_in[3];
    const float* rel_bias = (const float*)d_in[4];
    float* out = (float*)d_out;

    unsigned short* ws = (unsigned short*)d_ws;
    unsigned short* xb     = ws;                       // 4194304
    unsigned short* wqkvb  = xb + 4194304;             // 3145728
    unsigned short* wprojb = wqkvb + 3145728;          // 1048576
    unsigned short* qtb    = wprojb + 1048576;         // 4194304 (B,H,hd,T) TRANSPOSED, pre-scaled
    unsigned short* kb     = qtb + 4194304;            // 4194304 (B,H,T,hd)
    unsigned short* vtb    = kb + 4194304;             // 4194304 (B,H,hd,T) TRANSPOSED
    unsigned short* yab    = vtb + 4194304;            // 4194304 (B,T,C)

    cvt_all_kernel<<<4096, 256, 0, stream>>>(x, w_qkv, w_proj, xb, wqkvb, wprojb);
    gemm_qkv_kernel<<<dim3(24, 32), 256, 0, stream>>>(xb, wqkvb, qtb, kb, vtb);
    attn_kernel<<<dim3(16, 32), 512, 0, stream>>>(qtb, kb, vtb, rel_bias, yab);
    gemm_proj_kernel<<<dim3(8, 32), 512, 0, stream>>>(yab, wprojb, out, b_proj);
}

// Round 6
// 169.891 us; speedup vs baseline: 1.0739x; 1.0739x over previous
//
#include <hip/hip_runtime.h>

// B=2, T=2048, C=1024, H=16, hd=64, LOCAL_WINDOW=512, MAX_REL_DIST=128
#define T_SEQ 2048
#define HD 64

typedef float f32x4 __attribute__((ext_vector_type(4)));
typedef __bf16 bf16x8 __attribute__((ext_vector_type(8)));
typedef unsigned short ushort4v __attribute__((ext_vector_type(4)));
typedef unsigned short ushort8v __attribute__((ext_vector_type(8)));

__device__ __forceinline__ unsigned short f2bf(float f) {
    unsigned u = __builtin_bit_cast(unsigned, f);
    u += 0x7fffu + ((u >> 16) & 1u);
    return (unsigned short)(u >> 16);
}

__device__ __forceinline__ void gll16(const void* g, void* lds) {
    __builtin_amdgcn_global_load_lds(
        (const __attribute__((address_space(1))) unsigned int*)g,
        (__attribute__((address_space(3))) unsigned int*)lds, 16, 0, 0);
}

__device__ __forceinline__ bf16x8 ldfrag(const unsigned short* p) {
    return __builtin_bit_cast(bf16x8, *reinterpret_cast<const ushort8v*>(p));
}

// fused fp32->bf16 convert for x / w_qkv / w_proj (one launch)
__global__ __launch_bounds__(256)
void cvt_all_kernel(const float* __restrict__ x, const float* __restrict__ wq,
                    const float* __restrict__ wp, unsigned short* __restrict__ xb,
                    unsigned short* __restrict__ wqb, unsigned short* __restrict__ wpb)
{
    int bid = blockIdx.x;
    const float* s; unsigned short* d; int off;
    if (bid < 2048)      { s = x;  d = xb;  off = bid; }
    else if (bid < 3584) { s = wq; d = wqb; off = bid - 2048; }
    else                 { s = wp; d = wpb; off = bid - 3584; }
    int i = (off * 256 + threadIdx.x) * 8;
    f32x4 a = *reinterpret_cast<const f32x4*>(s + i);
    f32x4 b = *reinterpret_cast<const f32x4*>(s + i + 4);
    ushort8v o;
#pragma unroll
    for (int j = 0; j < 4; ++j) { o[j] = f2bf(a[j]); o[4 + j] = f2bf(b[j]); }
    *reinterpret_cast<ushort8v*>(d + i) = o;
}

// QKV GEMM: out[n][m] = sum_k A[n][k]*W[m][k], K=1024, 128x128 tile, 256 thr.
// q stored (B,H,T,hd) pre-scaled by 0.125; k stored (B,H,T,hd);
// v stored TRANSPOSED (B,H,hd,T) (scalar b16 scatter — proven 45us config).
__global__ __launch_bounds__(256)
void gemm_qkv_kernel(const unsigned short* __restrict__ A, const unsigned short* __restrict__ W,
                     unsigned short* __restrict__ qo, unsigned short* __restrict__ ko,
                     unsigned short* __restrict__ vo)
{
    constexpr int K = 1024;
    __shared__ unsigned short As[128 * 32];
    __shared__ unsigned short Bs[128 * 32];
    const int t = threadIdx.x;
    const int m0 = blockIdx.x * 128, n0 = blockIdx.y * 128;
    const int lane = t & 63, w = t >> 6;
    const int wy = w >> 1, wx = w & 1;
    const int l15 = lane & 15, quad = lane >> 4;

    f32x4 acc[4][4] = {};
    const char* Ab = (const char*)A;
    const char* Wb = (const char*)W;

    for (int kcl = 0; kcl < K; kcl += 32) {
#pragma unroll
        for (int i = 0; i < 2; ++i) {
            int c = w * 2 + i;                  // 1KB chunk 0..7
            int lin = c * 1024 + lane * 16;
            int row = lin >> 6;
            int kc = ((lin & 63) >> 4) ^ (row & 3);   // xor-swizzled 16B chunk
            gll16(Ab + ((size_t)(n0 + row) * K + kcl + kc * 8) * 2, (char*)As + c * 1024);
            gll16(Wb + ((size_t)(m0 + row) * K + kcl + kc * 8) * 2, (char*)Bs + c * 1024);
        }
        __syncthreads();
        bf16x8 af[4], bfr[4];
#pragma unroll
        for (int nt = 0; nt < 4; ++nt)
            af[nt] = ldfrag(As + (wy * 64 + nt * 16 + l15) * 32 + ((quad ^ (l15 & 3)) * 8));
#pragma unroll
        for (int mt = 0; mt < 4; ++mt)
            bfr[mt] = ldfrag(Bs + (wx * 64 + mt * 16 + l15) * 32 + ((quad ^ (l15 & 3)) * 8));
#pragma unroll
        for (int nt = 0; nt < 4; ++nt)
#pragma unroll
            for (int mt = 0; mt < 4; ++mt)
                acc[nt][mt] = __builtin_amdgcn_mfma_f32_16x16x32_bf16(af[nt], bfr[mt], acc[nt][mt], 0, 0, 0);
        __syncthreads();
    }

    const int s = m0 >> 10;   // block-uniform: which of q/k/v this block writes
#pragma unroll
    for (int nt = 0; nt < 4; ++nt) {
#pragma unroll
        for (int mt = 0; mt < 4; ++mt) {
            const int m = m0 + wx * 64 + mt * 16 + l15;
            const int h = (m >> 6) & 15, d = m & 63;
#pragma unroll
            for (int r = 0; r < 4; ++r) {
                const int n = n0 + wy * 64 + nt * 16 + quad * 4 + r;
                const int bb = n >> 11, tt = n & 2047;
                float val = acc[nt][mt][r];
                if (s == 0)
                    qo[((size_t)((bb << 4) + h) * T_SEQ + tt) * HD + d] = f2bf(val * 0.125f);
                else if (s == 1)
                    ko[((size_t)((bb << 4) + h) * T_SEQ + tt) * HD + d] = f2bf(val);
                else
                    vo[((size_t)((bb << 4) + h) * HD + d) * T_SEQ + tt] = f2bf(val);
            }
        }
    }
}

// Proj GEMM: 64x64 tile, 256 threads (4 waves 2x2, each wave 32x32), grid (16,64)=1024 blocks.
// Latency-bound regime: max parallelism beats per-block MFMA efficiency.
__global__ __launch_bounds__(256)
void gemm_proj_kernel(const unsigned short* __restrict__ A, const unsigned short* __restrict__ W,
                      float* __restrict__ o0, const float* __restrict__ bias)
{
    constexpr int K = 1024;
    __shared__ unsigned short As[64 * 32];
    __shared__ unsigned short Bs[64 * 32];
    const int t = threadIdx.x;
    const int m0 = blockIdx.x * 64, n0 = blockIdx.y * 64;
    const int lane = t & 63, w = t >> 6;
    const int wy = w >> 1, wx = w & 1;     // wave tile: 32n x 32m
    const int l15 = lane & 15, quad = lane >> 4;

    f32x4 acc[2][2] = {};
    const char* Ab = (const char*)A;
    const char* Wb = (const char*)W;
    const int srow = t >> 2;                   // 0..63
    const int skc = (t & 3) ^ (srow & 3);      // xor-swizzled 16B chunk

    for (int kcl = 0; kcl < K; kcl += 32) {
        gll16(Ab + ((size_t)(n0 + srow) * K + kcl + skc * 8) * 2, (char*)As + w * 1024);
        gll16(Wb + ((size_t)(m0 + srow) * K + kcl + skc * 8) * 2, (char*)Bs + w * 1024);
        __syncthreads();
        bf16x8 af[2], bfr[2];
#pragma unroll
        for (int nt = 0; nt < 2; ++nt)
            af[nt] = ldfrag(As + (wy * 32 + nt * 16 + l15) * 32 + ((quad ^ (l15 & 3)) * 8));
#pragma unroll
        for (int mt = 0; mt < 2; ++mt)
            bfr[mt] = ldfrag(Bs + (wx * 32 + mt * 16 + l15) * 32 + ((quad ^ (l15 & 3)) * 8));
#pragma unroll
        for (int nt = 0; nt < 2; ++nt)
#pragma unroll
            for (int mt = 0; mt < 2; ++mt)
                acc[nt][mt] = __builtin_amdgcn_mfma_f32_16x16x32_bf16(af[nt], bfr[mt], acc[nt][mt], 0, 0, 0);
        __syncthreads();
    }

#pragma unroll
    for (int nt = 0; nt < 2; ++nt)
#pragma unroll
        for (int mt = 0; mt < 2; ++mt) {
            const int m = m0 + wx * 32 + mt * 16 + l15;
            const float bm = bias[m];
#pragma unroll
            for (int r = 0; r < 4; ++r) {
                const int n = n0 + wy * 32 + nt * 16 + quad * 4 + r;
                o0[(size_t)n * 1024 + m] = acc[nt][mt][r] + bm;
            }
        }
}

// S^T-formulation MFMA flash attention.
// grid (T/128, B*H), 512 threads = 8 waves; wave owns 16 q rows (q = q0+w*16+l15 per lane).
// S^T = K Q^T (A=K, B=Q loaded contiguously from natural (B,H,T,hd) q).
// O^T = V^T P (A=V^T from pre-transposed V, B=P via vectorized LDS round trip).
__global__ __launch_bounds__(512, 4)
void attn_kernel(const unsigned short* __restrict__ qg, const unsigned short* __restrict__ kg,
                 const unsigned short* __restrict__ vt, const float* __restrict__ rel_bias,
                 unsigned short* __restrict__ y)
{
    __shared__ unsigned short Ks[64 * 64];      // K tile [key][hd], 16B chunks xor-swizzled
    __shared__ unsigned short Vt[64 * 64];      // V^T tile [hd][key], same swizzle
    __shared__ unsigned short Pl[8 * 16 * 72];  // per-wave P [q(16)][key(64)+pad]
    __shared__ float bias_s[260];

    const int t = threadIdx.x;
    const int lane = t & 63, w = t >> 6;
    const int l15 = lane & 15, quad = lane >> 4;
    const int qt = blockIdx.x, bh = blockIdx.y;
    const int b = bh >> 4, h = bh & 15;
    const int q0 = qt << 7;
    const int qw0 = q0 + w * 16;
    const int q_row = qw0 + l15;
    const size_t base = (size_t)bh * T_SEQ * HD;   // same stride for q, k, v^t

    for (int i = t; i < 257; i += 512) bias_s[i] = rel_bias[i * 16 + h];

    // Q fragments (B operand: lane l15 = q col, k = quad*8+j): contiguous along hd
    // in natural (B,H,T,hd) layout. Scale pre-applied by producer.
    bf16x8 qf[2];
#pragma unroll
    for (int ks = 0; ks < 2; ++ks)
        qf[ks] = ldfrag(qg + base + (size_t)q_row * HD + ks * 32 + quad * 8);

    float m_r = -1e30f, l_r = 0.f;
    f32x4 Oacc[4] = {};                          // [mt over hd], col = q

    unsigned short* Pme = Pl + w * (16 * 72);
    // staging map: thread stages one 16B chunk of K and of V^T
    const int srow = t >> 3;                     // 0..63
    const int skc = (t & 7) ^ (srow & 7);        // global 16B chunk (xor-swizzled slot)

    const int kt0 = (qt * 2 > 8) ? (qt * 2 - 8) : 0;
    const int kt1 = qt * 2 + 1;

    for (int kt = kt0; kt <= kt1; ++kt) {
        gll16((const char*)(kg + base + (size_t)(kt * 64 + srow) * HD + skc * 8), (char*)Ks + w * 1024);
        gll16((const char*)(vt + base + (size_t)srow * T_SEQ + kt * 64 + skc * 8), (char*)Vt + w * 1024);
        __syncthreads();

        const int delta = qw0 - kt * 64;         // wave-uniform
        if (delta >= 0 && delta <= 560) {        // wave has work this tile
            // S^T = K Q^T
            f32x4 Sacc[4] = {};
#pragma unroll
            for (int ks = 0; ks < 2; ++ks)
#pragma unroll
                for (int ct = 0; ct < 4; ++ct) {
                    bf16x8 kf = ldfrag(Ks + (ct * 16 + l15) * 64 + (((ks * 4 + quad) ^ (l15 & 7)) * 8));
                    Sacc[ct] = __builtin_amdgcn_mfma_f32_16x16x32_bf16(kf, qf[ks], Sacc[ct], 0, 0, 0);
                }

            float sv[4][4];
            if (delta >= 192 && delta <= 496) {
                // fast path: no mask possible, bias == bias[256] for all pairs
                const float bC = bias_s[256];
#pragma unroll
                for (int ct = 0; ct < 4; ++ct)
#pragma unroll
                    for (int r = 0; r < 4; ++r) sv[ct][r] = Sacc[ct][r] + bC;
            } else {
#pragma unroll
                for (int ct = 0; ct < 4; ++ct)
#pragma unroll
                    for (int r = 0; r < 4; ++r) {
                        int diff = q_row - (kt * 64 + ct * 16 + quad * 4 + r);
                        float bb = bias_s[(diff < 128 ? diff : 128) + 128];
                        float s = Sacc[ct][r] + bb;
                        sv[ct][r] = (diff < 0 || diff > 512) ? -1e30f : s;
                    }
            }

            // online softmax (per-lane scalar state; reduce across quad groups)
            float mx = -1e30f;
#pragma unroll
            for (int ct = 0; ct < 4; ++ct)
#pragma unroll
                for (int r = 0; r < 4; ++r) mx = fmaxf(mx, sv[ct][r]);
            mx = fmaxf(mx, __shfl_xor(mx, 16, 64));
            mx = fmaxf(mx, __shfl_xor(mx, 32, 64));
            float mn = fmaxf(m_r, mx);
            float alpha = __expf(m_r - mn);
            m_r = mn;
            float ps = 0.f;
            float p[4][4];
#pragma unroll
            for (int ct = 0; ct < 4; ++ct)
#pragma unroll
                for (int r = 0; r < 4; ++r) { p[ct][r] = __expf(sv[ct][r] - mn); ps += p[ct][r]; }
            ps += __shfl_xor(ps, 16, 64);
            ps += __shfl_xor(ps, 32, 64);
            l_r = l_r * alpha + ps;

            // P -> wave-private LDS (vectorized b64: lane's 4 keys are contiguous)
#pragma unroll
            for (int ct = 0; ct < 4; ++ct) {
                ushort4v pw;
#pragma unroll
                for (int j = 0; j < 4; ++j) pw[j] = f2bf(p[ct][j]);
                *reinterpret_cast<ushort4v*>(Pme + l15 * 72 + ct * 16 + quad * 4) = pw;
            }
#pragma unroll
            for (int mt = 0; mt < 4; ++mt) Oacc[mt] *= alpha;
#pragma unroll
            for (int ks = 0; ks < 2; ++ks) {
                bf16x8 pf = ldfrag(Pme + l15 * 72 + ks * 32 + quad * 8);
#pragma unroll
                for (int mt = 0; mt < 4; ++mt) {
                    bf16x8 vf = ldfrag(Vt + (mt * 16 + l15) * 64 + (((ks * 4 + quad) ^ (l15 & 7)) * 8));
                    Oacc[mt] = __builtin_amdgcn_mfma_f32_16x16x32_bf16(vf, pf, Oacc[mt], 0, 0, 0);
                }
            }
        }
        __syncthreads();
    }

    // normalize + write: lane's 16 outputs are one q row, contiguous per mt (b64 stores)
    const float inv = 1.0f / l_r;
    unsigned short* yp = y + ((size_t)b * T_SEQ + q_row) * 1024 + h * 64;
#pragma unroll
    for (int mt = 0; mt < 4; ++mt) {
        ushort4v o;
#pragma unroll
        for (int j = 0; j < 4; ++j) o[j] = f2bf(Oacc[mt][j] * inv);
        *reinterpret_cast<ushort4v*>(yp + mt * 16 + quad * 4) = o;
    }
}

extern "C" void kernel_launch(void* const* d_in, const int* in_sizes, int n_in,
                              void* d_out, int out_size, void* d_ws, size_t ws_size,
                              hipStream_t stream)
{
    (void)in_sizes; (void)n_in; (void)out_size; (void)ws_size;
    const float* x        = (const float*)d_in[0];
    const float* w_qkv    = (const float*)d_in[1];
    const float* w_proj   = (const float*)d_in[2];
    const float* b_proj   = (const float*)d_in[3];
    const float* rel_bias = (const float*)d_in[4];
    float* out = (float*)d_out;

    unsigned short* ws = (unsigned short*)d_ws;
    unsigned short* xb     = ws;                       // 4194304
    unsigned short* wqkvb  = xb + 4194304;             // 3145728
    unsigned short* wprojb = wqkvb + 3145728;          // 1048576
    unsigned short* qb     = wprojb + 1048576;         // 4194304 (B,H,T,hd), pre-scaled
    unsigned short* kb     = qb + 4194304;             // 4194304 (B,H,T,hd)
    unsigned short* vtb    = kb + 4194304;             // 4194304 (B,H,hd,T) TRANSPOSED
    unsigned short* yab    = vtb + 4194304;            // 4194304 (B,T,C)

    cvt_all_kernel<<<4096, 256, 0, stream>>>(x, w_qkv, w_proj, xb, wqkvb, wprojb);
    gemm_qkv_kernel<<<dim3(24, 32), 256, 0, stream>>>(xb, wqkvb, qb, kb, vtb);
    attn_kernel<<<dim3(16, 32), 512, 0, stream>>>(qb, kb, vtb, rel_bias, yab);
    gemm_proj_kernel<<<dim3(16, 64), 256, 0, stream>>>(yab, wprojb, out, b_proj);
}

// Round 7
// 169.289 us; speedup vs baseline: 1.0777x; 1.0036x over previous
//
#include <hip/hip_runtime.h>

// B=2, T=2048, C=1024, H=16, hd=64, LOCAL_WINDOW=512, MAX_REL_DIST=128
#define T_SEQ 2048
#define HD 64

typedef float f32x4 __attribute__((ext_vector_type(4)));
typedef __bf16 bf16x8 __attribute__((ext_vector_type(8)));
typedef unsigned short ushort4v __attribute__((ext_vector_type(4)));
typedef unsigned short ushort8v __attribute__((ext_vector_type(8)));

__device__ __forceinline__ unsigned short f2bf(float f) {
    unsigned u = __builtin_bit_cast(unsigned, f);
    u += 0x7fffu + ((u >> 16) & 1u);
    return (unsigned short)(u >> 16);
}

__device__ __forceinline__ void gll16(const void* g, void* lds) {
    __builtin_amdgcn_global_load_lds(
        (const __attribute__((address_space(1))) unsigned int*)g,
        (__attribute__((address_space(3))) unsigned int*)lds, 16, 0, 0);
}

__device__ __forceinline__ bf16x8 ldfrag(const unsigned short* p) {
    return __builtin_bit_cast(bf16x8, *reinterpret_cast<const ushort8v*>(p));
}

// fused fp32->bf16 convert for x / w_qkv / w_proj (one launch)
__global__ __launch_bounds__(256)
void cvt_all_kernel(const float* __restrict__ x, const float* __restrict__ wq,
                    const float* __restrict__ wp, unsigned short* __restrict__ xb,
                    unsigned short* __restrict__ wqb, unsigned short* __restrict__ wpb)
{
    int bid = blockIdx.x;
    const float* s; unsigned short* d; int off;
    if (bid < 2048)      { s = x;  d = xb;  off = bid; }
    else if (bid < 3584) { s = wq; d = wqb; off = bid - 2048; }
    else                 { s = wp; d = wpb; off = bid - 3584; }
    int i = (off * 256 + threadIdx.x) * 8;
    f32x4 a = *reinterpret_cast<const f32x4*>(s + i);
    f32x4 b = *reinterpret_cast<const f32x4*>(s + i + 4);
    ushort8v o;
#pragma unroll
    for (int j = 0; j < 4; ++j) { o[j] = f2bf(a[j]); o[4 + j] = f2bf(b[j]); }
    *reinterpret_cast<ushort8v*>(d + i) = o;
}

// QKV GEMM: out[n][m] = sum_k A[n][k]*W[m][k], K=1024, 128x128 tile, 512 thr (8 waves).
// Wave tile 32n x 64m (acc 2x4). 24 waves/CU at grid 768 for latency hiding.
// q stored (B,H,T,hd) pre-scaled by 0.125; k stored (B,H,T,hd);
// v stored TRANSPOSED (B,H,hd,T) (scalar b16 scatter).
__global__ __launch_bounds__(512, 6)
void gemm_qkv_kernel(const unsigned short* __restrict__ A, const unsigned short* __restrict__ W,
                     unsigned short* __restrict__ qo, unsigned short* __restrict__ ko,
                     unsigned short* __restrict__ vo)
{
    constexpr int K = 1024;
    __shared__ unsigned short As[128 * 32];
    __shared__ unsigned short Bs[128 * 32];
    const int t = threadIdx.x;
    const int m0 = blockIdx.x * 128, n0 = blockIdx.y * 128;
    const int lane = t & 63, w = t >> 6;       // 8 waves
    const int wy = w >> 1, wx = w & 1;         // wy 0..3 over n(32), wx 0..1 over m(64)
    const int l15 = lane & 15, quad = lane >> 4;

    f32x4 acc[2][4] = {};
    const char* Ab = (const char*)A;
    const char* Wb = (const char*)W;

    // staging: wave w stages 1KB chunk w of As and Bs (16 rows each)
    const int srow = w * 16 + (lane >> 2);                 // 0..127
    const int slot = (lane & 3) ^ ((lane >> 2) & 3);       // xor-swizzled 16B slot

    for (int kcl = 0; kcl < K; kcl += 32) {
        gll16(Ab + ((size_t)(n0 + srow) * K + kcl + slot * 8) * 2, (char*)As + w * 1024);
        gll16(Wb + ((size_t)(m0 + srow) * K + kcl + slot * 8) * 2, (char*)Bs + w * 1024);
        __syncthreads();
        bf16x8 af[2], bfr[4];
#pragma unroll
        for (int nt = 0; nt < 2; ++nt)
            af[nt] = ldfrag(As + (wy * 32 + nt * 16 + l15) * 32 + ((quad ^ (l15 & 3)) * 8));
#pragma unroll
        for (int mt = 0; mt < 4; ++mt)
            bfr[mt] = ldfrag(Bs + (wx * 64 + mt * 16 + l15) * 32 + ((quad ^ (l15 & 3)) * 8));
#pragma unroll
        for (int nt = 0; nt < 2; ++nt)
#pragma unroll
            for (int mt = 0; mt < 4; ++mt)
                acc[nt][mt] = __builtin_amdgcn_mfma_f32_16x16x32_bf16(af[nt], bfr[mt], acc[nt][mt], 0, 0, 0);
        __syncthreads();
    }

    const int s = m0 >> 10;   // block-uniform: which of q/k/v this block writes
#pragma unroll
    for (int nt = 0; nt < 2; ++nt) {
#pragma unroll
        for (int mt = 0; mt < 4; ++mt) {
            const int m = m0 + wx * 64 + mt * 16 + l15;
            const int h = (m >> 6) & 15, d = m & 63;
#pragma unroll
            for (int r = 0; r < 4; ++r) {
                const int n = n0 + wy * 32 + nt * 16 + quad * 4 + r;
                const int bb = n >> 11, tt = n & 2047;
                float val = acc[nt][mt][r];
                if (s == 0)
                    qo[((size_t)((bb << 4) + h) * T_SEQ + tt) * HD + d] = f2bf(val * 0.125f);
                else if (s == 1)
                    ko[((size_t)((bb << 4) + h) * T_SEQ + tt) * HD + d] = f2bf(val);
                else
                    vo[((size_t)((bb << 4) + h) * HD + d) * T_SEQ + tt] = f2bf(val);
            }
        }
    }
}

// Proj GEMM: 64x64 tile, 256 threads (4 waves 2x2, each wave 32x32), grid (16,64)=1024 blocks.
__global__ __launch_bounds__(256)
void gemm_proj_kernel(const unsigned short* __restrict__ A, const unsigned short* __restrict__ W,
                      float* __restrict__ o0, const float* __restrict__ bias)
{
    constexpr int K = 1024;
    __shared__ unsigned short As[64 * 32];
    __shared__ unsigned short Bs[64 * 32];
    const int t = threadIdx.x;
    const int m0 = blockIdx.x * 64, n0 = blockIdx.y * 64;
    const int lane = t & 63, w = t >> 6;
    const int wy = w >> 1, wx = w & 1;     // wave tile: 32n x 32m
    const int l15 = lane & 15, quad = lane >> 4;

    f32x4 acc[2][2] = {};
    const char* Ab = (const char*)A;
    const char* Wb = (const char*)W;
    const int srow = t >> 2;                   // 0..63
    const int skc = (t & 3) ^ (srow & 3);      // xor-swizzled 16B chunk

    for (int kcl = 0; kcl < K; kcl += 32) {
        gll16(Ab + ((size_t)(n0 + srow) * K + kcl + skc * 8) * 2, (char*)As + w * 1024);
        gll16(Wb + ((size_t)(m0 + srow) * K + kcl + skc * 8) * 2, (char*)Bs + w * 1024);
        __syncthreads();
        bf16x8 af[2], bfr[2];
#pragma unroll
        for (int nt = 0; nt < 2; ++nt)
            af[nt] = ldfrag(As + (wy * 32 + nt * 16 + l15) * 32 + ((quad ^ (l15 & 3)) * 8));
#pragma unroll
        for (int mt = 0; mt < 2; ++mt)
            bfr[mt] = ldfrag(Bs + (wx * 32 + mt * 16 + l15) * 32 + ((quad ^ (l15 & 3)) * 8));
#pragma unroll
        for (int nt = 0; nt < 2; ++nt)
#pragma unroll
            for (int mt = 0; mt < 2; ++mt)
                acc[nt][mt] = __builtin_amdgcn_mfma_f32_16x16x32_bf16(af[nt], bfr[mt], acc[nt][mt], 0, 0, 0);
        __syncthreads();
    }

#pragma unroll
    for (int nt = 0; nt < 2; ++nt)
#pragma unroll
        for (int mt = 0; mt < 2; ++mt) {
            const int m = m0 + wx * 32 + mt * 16 + l15;
            const float bm = bias[m];
#pragma unroll
            for (int r = 0; r < 4; ++r) {
                const int n = n0 + wy * 32 + nt * 16 + quad * 4 + r;
                o0[(size_t)n * 1024 + m] = acc[nt][mt][r] + bm;
            }
        }
}

// S^T-formulation MFMA flash attention, XCD-swizzled 1-D grid of 512 blocks.
// Each XCD (flat%8) owns 4 heads x 16 q-tiles -> K/V stay L2-local (2MB/XCD).
__global__ __launch_bounds__(512, 4)
void attn_kernel(const unsigned short* __restrict__ qg, const unsigned short* __restrict__ kg,
                 const unsigned short* __restrict__ vt, const float* __restrict__ rel_bias,
                 unsigned short* __restrict__ y)
{
    __shared__ unsigned short Ks[64 * 64];      // K tile [key][hd], 16B chunks xor-swizzled
    __shared__ unsigned short Vt[64 * 64];      // V^T tile [hd][key], same swizzle
    __shared__ unsigned short Pl[8 * 16 * 72];  // per-wave P [q(16)][key(64)+pad]
    __shared__ float bias_s[260];

    const int t = threadIdx.x;
    const int lane = t & 63, w = t >> 6;
    const int l15 = lane & 15, quad = lane >> 4;
    // XCD-aware decode: xcd = flat%8 gets heads [xcd*4, xcd*4+4) x all 16 q-tiles
    const int flat = blockIdx.x;
    const int xcd = flat & 7, within = flat >> 3;
    const int bh = xcd * 4 + (within >> 4);
    const int qt = within & 15;
    const int b = bh >> 4, h = bh & 15;
    const int q0 = qt << 7;
    const int qw0 = q0 + w * 16;
    const int q_row = qw0 + l15;
    const size_t base = (size_t)bh * T_SEQ * HD;   // same stride for q, k, v^t

    for (int i = t; i < 257; i += 512) bias_s[i] = rel_bias[i * 16 + h];

    // Q fragments (B operand: lane l15 = q col, k = quad*8+j): contiguous along hd.
    bf16x8 qf[2];
#pragma unroll
    for (int ks = 0; ks < 2; ++ks)
        qf[ks] = ldfrag(qg + base + (size_t)q_row * HD + ks * 32 + quad * 8);

    float m_r = -1e30f, l_r = 0.f;
    f32x4 Oacc[4] = {};                          // [mt over hd], col = q

    unsigned short* Pme = Pl + w * (16 * 72);
    const int srow = t >> 3;                     // 0..63
    const int skc = (t & 7) ^ (srow & 7);        // xor-swizzled global 16B chunk

    const int kt0 = (qt * 2 > 8) ? (qt * 2 - 8) : 0;
    const int kt1 = qt * 2 + 1;

    for (int kt = kt0; kt <= kt1; ++kt) {
        gll16((const char*)(kg + base + (size_t)(kt * 64 + srow) * HD + skc * 8), (char*)Ks + w * 1024);
        gll16((const char*)(vt + base + (size_t)srow * T_SEQ + kt * 64 + skc * 8), (char*)Vt + w * 1024);
        __syncthreads();

        const int delta = qw0 - kt * 64;         // wave-uniform
        if (delta >= 0 && delta <= 560) {        // wave has work this tile
            // S^T = K Q^T
            f32x4 Sacc[4] = {};
#pragma unroll
            for (int ks = 0; ks < 2; ++ks)
#pragma unroll
                for (int ct = 0; ct < 4; ++ct) {
                    bf16x8 kf = ldfrag(Ks + (ct * 16 + l15) * 64 + (((ks * 4 + quad) ^ (l15 & 7)) * 8));
                    Sacc[ct] = __builtin_amdgcn_mfma_f32_16x16x32_bf16(kf, qf[ks], Sacc[ct], 0, 0, 0);
                }

            float sv[4][4];
            if (delta >= 192 && delta <= 496) {
                // fast path: no mask possible, bias == bias[256] for all pairs
                const float bC = bias_s[256];
#pragma unroll
                for (int ct = 0; ct < 4; ++ct)
#pragma unroll
                    for (int r = 0; r < 4; ++r) sv[ct][r] = Sacc[ct][r] + bC;
            } else {
#pragma unroll
                for (int ct = 0; ct < 4; ++ct)
#pragma unroll
                    for (int r = 0; r < 4; ++r) {
                        int diff = q_row - (kt * 64 + ct * 16 + quad * 4 + r);
                        float bb = bias_s[(diff < 128 ? diff : 128) + 128];
                        float s = Sacc[ct][r] + bb;
                        sv[ct][r] = (diff < 0 || diff > 512) ? -1e30f : s;
                    }
            }

            // online softmax (per-lane scalar state; reduce across quad groups)
            float mx = -1e30f;
#pragma unroll
            for (int ct = 0; ct < 4; ++ct)
#pragma unroll
                for (int r = 0; r < 4; ++r) mx = fmaxf(mx, sv[ct][r]);
            mx = fmaxf(mx, __shfl_xor(mx, 16, 64));
            mx = fmaxf(mx, __shfl_xor(mx, 32, 64));
            float mn = fmaxf(m_r, mx);
            float alpha = __expf(m_r - mn);
            m_r = mn;
            float ps = 0.f;
            float p[4][4];
#pragma unroll
            for (int ct = 0; ct < 4; ++ct)
#pragma unroll
                for (int r = 0; r < 4; ++r) { p[ct][r] = __expf(sv[ct][r] - mn); ps += p[ct][r]; }
            ps += __shfl_xor(ps, 16, 64);
            ps += __shfl_xor(ps, 32, 64);
            l_r = l_r * alpha + ps;

            // P -> wave-private LDS (vectorized b64: lane's 4 keys are contiguous)
#pragma unroll
            for (int ct = 0; ct < 4; ++ct) {
                ushort4v pw;
#pragma unroll
                for (int j = 0; j < 4; ++j) pw[j] = f2bf(p[ct][j]);
                *reinterpret_cast<ushort4v*>(Pme + l15 * 72 + ct * 16 + quad * 4) = pw;
            }
#pragma unroll
            for (int mt = 0; mt < 4; ++mt) Oacc[mt] *= alpha;
#pragma unroll
            for (int ks = 0; ks < 2; ++ks) {
                bf16x8 pf = ldfrag(Pme + l15 * 72 + ks * 32 + quad * 8);
#pragma unroll
                for (int mt = 0; mt < 4; ++mt) {
                    bf16x8 vf = ldfrag(Vt + (mt * 16 + l15) * 64 + (((ks * 4 + quad) ^ (l15 & 7)) * 8));
                    Oacc[mt] = __builtin_amdgcn_mfma_f32_16x16x32_bf16(vf, pf, Oacc[mt], 0, 0, 0);
                }
            }
        }
        __syncthreads();
    }

    // normalize + write: lane's 16 outputs are one q row, contiguous per mt (b64 stores)
    const float inv = 1.0f / l_r;
    unsigned short* yp = y + ((size_t)b * T_SEQ + q_row) * 1024 + h * 64;
#pragma unroll
    for (int mt = 0; mt < 4; ++mt) {
        ushort4v o;
#pragma unroll
        for (int j = 0; j < 4; ++j) o[j] = f2bf(Oacc[mt][j] * inv);
        *reinterpret_cast<ushort4v*>(yp + mt * 16 + quad * 4) = o;
    }
}

extern "C" void kernel_launch(void* const* d_in, const int* in_sizes, int n_in,
                              void* d_out, int out_size, void* d_ws, size_t ws_size,
                              hipStream_t stream)
{
    (void)in_sizes; (void)n_in; (void)out_size; (void)ws_size;
    const float* x        = (const float*)d_in[0];
    const float* w_qkv    = (const float*)d_in[1];
    const float* w_proj   = (const float*)d_in[2];
    const float* b_proj   = (const float*)d_in[3];
    const float* rel_bias = (const float*)d_in[4];
    float* out = (float*)d_out;

    unsigned short* ws = (unsigned short*)d_ws;
    unsigned short* xb     = ws;                       // 4194304
    unsigned short* wqkvb  = xb + 4194304;             // 3145728
    unsigned short* wprojb = wqkvb + 3145728;          // 1048576
    unsigned short* qb     = wprojb + 1048576;         // 4194304 (B,H,T,hd), pre-scaled
    unsigned short* kb     = qb + 4194304;             // 4194304 (B,H,T,hd)
    unsigned short* vtb    = kb + 4194304;             // 4194304 (B,H,hd,T) TRANSPOSED
    unsigned short* yab    = vtb + 4194304;            // 4194304 (B,T,C)

    cvt_all_kernel<<<4096, 256, 0, stream>>>(x, w_qkv, w_proj, xb, wqkvb, wprojb);
    gemm_qkv_kernel<<<dim3(24, 32), 512, 0, stream>>>(xb, wqkvb, qb, kb, vtb);
    attn_kernel<<<512, 512, 0, stream>>>(qb, kb, vtb, rel_bias, yab);
    gemm_proj_kernel<<<dim3(16, 64), 256, 0, stream>>>(yab, wprojb, out, b_proj);
}